// Round 5
// baseline (312.308 us; speedup 1.0000x reference)
//
#include <hip/hip_runtime.h>
#include <hip/hip_bf16.h>
#include <math.h>

// BinaryTreeLSTM — round 5: packed Xcat/Wcat (branch-free unit-stride GEMM),
// stable XCD<->weight-slab affinity for cross-level L2 residency, deeper
// K-split on mid/tail levels.
//
// Wcat[4096][3072]: row e = gate-col (g*1024+j -> W row g*2048+j), cols
//   [0,1024) = W_ih, [1024,3072) = W_hh.
// Xcat: per-level slabs, level k at row off(k) = 4096 - 2^(k+1), n=2^k rows
//   of 3072: cols [0,1024) = bf16(emb[n-1+m]), cols [1024,3072) = h_cat
//   (written by act of level k+1).

#define HDIM 1024
#define TREE_DEPTH 12
#define GCOLS 4096

typedef unsigned short u16;
typedef unsigned int u32;
typedef __attribute__((ext_vector_type(8))) short bf16x8;
typedef __attribute__((ext_vector_type(4))) float f32x4;

__device__ __forceinline__ void gload16(const void* g, void* l) {
    __builtin_amdgcn_global_load_lds(
        (const __attribute__((address_space(1))) u32*)g,
        (__attribute__((address_space(3))) u32*)l, 16, 0, 0);
}

__device__ __forceinline__ u16 f2bf(float f) {
    __hip_bfloat16 h = __float2bfloat16(f);
    return *reinterpret_cast<u16*>(&h);
}

// ---------------------------------------------------------------- converts
__global__ void bias_kernel(const float* __restrict__ b_ih,
                            const float* __restrict__ b_hh,
                            float* __restrict__ bg) {
    int idx = blockIdx.x * blockDim.x + threadIdx.x;   // 0..4095
    int g = idx >> 10, j = idx & 1023;
    int r = g * 2048 + j;
    bg[idx] = b_ih[r] + b_hh[r];
}

// Pack W_ih|W_hh -> Wcat[4096][3072] bf16, with XCD-affine row order:
// row e is written by a block whose linear id % 8 == (e/128) % 8.
__global__ void pack_w(const float* __restrict__ Wih,
                       const float* __restrict__ Whh,
                       u16* __restrict__ Wcat) {
    const int b = blockIdx.x;          // 0..4095
    const int seg = blockIdx.y;        // 0..2
    const int x = b & 7, t = b >> 3;   // t in [0,512)
    const int e = x * 128 + (t & 127) + (t >> 7) * 1024;   // (e/128)%8 == x
    const int wr = (e >> 10) * 2048 + (e & 1023);
    const int col = threadIdx.x * 4;   // 0..1020
    float4 v;
    if (seg == 0)
        v = *reinterpret_cast<const float4*>(Wih + (size_t)wr * 1024 + col);
    else
        v = *reinterpret_cast<const float4*>(Whh + (size_t)wr * 2048 + (seg - 1) * 1024 + col);
    uint2 p = make_uint2((u32)f2bf(v.x) | ((u32)f2bf(v.y) << 16),
                         (u32)f2bf(v.z) | ((u32)f2bf(v.w) << 16));
    *reinterpret_cast<uint2*>(Wcat + (size_t)e * 3072 + seg * 1024 + col) = p;
}

// Scatter emb rows into each level's Xcat slab (x-part).
__global__ void conv_emb_cat(const float* __restrict__ emb, u16* __restrict__ Xcat) {
    const int r = blockIdx.x;                 // 0..4094
    const int k = 31 - __builtin_clz(r + 1);  // level
    const int m = (r + 1) - (1 << k);
    const size_t drow = (size_t)(4096 - (2 << k) + m);
    const int col = threadIdx.x * 4;
    float4 v = *reinterpret_cast<const float4*>(emb + (size_t)r * 1024 + col);
    uint2 p = make_uint2((u32)f2bf(v.x) | ((u32)f2bf(v.y) << 16),
                         (u32)f2bf(v.z) | ((u32)f2bf(v.w) << 16));
    *reinterpret_cast<uint2*>(Xcat + drow * 3072 + col) = p;
}

// ------------------------------------------------------- block-id unswizzle
// Linear block id -> (mt, ct, ks) such that weight slab s = sl*8 + (b&7):
// all blocks of slab s land on XCD s%8 (== ct%8 since 8|gy), at every level.
__device__ __forceinline__ void unswizzle(int gx, int gy, int& mt, int& ct, int& ks) {
    int b = blockIdx.x + gx * (blockIdx.y + gy * blockIdx.z);
    const int x = b & 7, t = b >> 3;
    mt = t % gx;
    const int sl = t / gx;
    const int s = sl * 8 + x;
    ct = s % gy;
    ks = s / gy;
}

// ---------------------------------------------------------------- big GEMM
// n multiple of 128. Tile 128x128, BK=32, 4 waves (64x64 each).
__global__ __launch_bounds__(256) void gemm_big(
    const u16* __restrict__ A,       // level slab: n x 3072
    const u16* __restrict__ W,       // Wcat: 4096 x 3072
    float* __restrict__ partials,    // KS slabs of n*4096
    int n, int kchunk)
{
    __shared__ u16 As[128][32];
    __shared__ u16 Bs[128][32];

    int mt, ct, ks;
    unswizzle(gridDim.x, gridDim.y, mt, ct, ks);

    const int m0 = mt * 128;
    const int c0 = ct * 128;
    const int kbeg = ks * kchunk;
    float* gout = partials + (size_t)ks * n * GCOLS;

    const int tid  = threadIdx.x;
    const int lane = tid & 63;
    const int w    = tid >> 6;
    const int wr   = (w >> 1) * 64;
    const int wc   = (w & 1) * 64;

    f32x4 acc[4][4];
    #pragma unroll
    for (int i = 0; i < 4; ++i)
        #pragma unroll
        for (int j = 0; j < 4; ++j)
            acc[i][j] = f32x4{0.f, 0.f, 0.f, 0.f};

    const int crow = lane >> 2;        // 0..15
    const int ck   = (lane & 3) * 8;   // 0,8,16,24

    // per-lane staging pointers (unit-stride walk, no branches in loop)
    const u16* pA0 = A + (size_t)(m0 + (w * 2 + 0) * 16 + crow) * 3072 + kbeg + ck;
    const u16* pA1 = A + (size_t)(m0 + (w * 2 + 1) * 16 + crow) * 3072 + kbeg + ck;
    const u16* pB0 = W + (size_t)(c0 + (w * 2 + 0) * 16 + crow) * 3072 + kbeg + ck;
    const u16* pB1 = W + (size_t)(c0 + (w * 2 + 1) * 16 + crow) * 3072 + kbeg + ck;

    const int fl = lane & 15;
    const int kb = (lane >> 4) * 8;

    for (int k0 = 0; k0 < kchunk; k0 += 32) {
        gload16(pA0, &As[(w * 2 + 0) * 16][0]);
        gload16(pA1, &As[(w * 2 + 1) * 16][0]);
        gload16(pB0, &Bs[(w * 2 + 0) * 16][0]);
        gload16(pB1, &Bs[(w * 2 + 1) * 16][0]);
        pA0 += 32; pA1 += 32; pB0 += 32; pB1 += 32;
        __syncthreads();

        bf16x8 a[4], b[4];
        #pragma unroll
        for (int i = 0; i < 4; ++i)
            a[i] = *reinterpret_cast<const bf16x8*>(&As[wr + i * 16 + fl][kb]);
        #pragma unroll
        for (int j = 0; j < 4; ++j)
            b[j] = *reinterpret_cast<const bf16x8*>(&Bs[wc + j * 16 + fl][kb]);
        #pragma unroll
        for (int i = 0; i < 4; ++i)
            #pragma unroll
            for (int j = 0; j < 4; ++j)
                acc[i][j] = __builtin_amdgcn_mfma_f32_16x16x32_bf16(a[i], b[j], acc[i][j], 0, 0, 0);
        __syncthreads();
    }

    const int rg = (lane >> 4) * 4;
    #pragma unroll
    for (int i = 0; i < 4; ++i)
        #pragma unroll
        for (int j = 0; j < 4; ++j) {
            const int c = c0 + wc + j * 16 + fl;
            #pragma unroll
            for (int r = 0; r < 4; ++r) {
                const int m = m0 + wr + i * 16 + rg + r;
                gout[(size_t)m * GCOLS + c] = acc[i][j][r];
            }
        }
}

// ---------------------------------------------------------------- small GEMM
// n <= 64. BM=16, BN=128 (same 128-col ct granularity as big), 4 waves,
// wave w covers cols w*32..w*32+31 (two 16x16 frags).
__global__ __launch_bounds__(256) void gemm_small(
    const u16* __restrict__ A,       // level slab: n x 3072
    const u16* __restrict__ W,       // Wcat
    float* __restrict__ partials,    // KS slabs of n*4096
    int n, int kchunk)
{
    __shared__ u16 As[16][32];
    __shared__ u16 Bs[128][32];

    int mt, ct, ks;
    unswizzle(gridDim.x, gridDim.y, mt, ct, ks);

    const int m0 = mt * 16;
    const int c0 = ct * 128;
    const int kbeg = ks * kchunk;

    const int tid  = threadIdx.x;
    const int lane = tid & 63;
    const int w    = tid >> 6;

    f32x4 acc0 = f32x4{0.f, 0.f, 0.f, 0.f};
    f32x4 acc1 = f32x4{0.f, 0.f, 0.f, 0.f};

    const int arow = tid >> 4;            // 0..15
    const int ak   = (tid & 15) * 2;      // 0..30 even
    const int crow = lane >> 2;
    const int ck   = (lane & 3) * 8;

    const int mA = m0 + arow;
    const u16* pA = A + (size_t)mA * 3072 + kbeg + ak;     // guarded
    const u16* pB0 = W + (size_t)(c0 + w * 32 + 0  + crow) * 3072 + kbeg + ck;
    const u16* pB1 = W + (size_t)(c0 + w * 32 + 16 + crow) * 3072 + kbeg + ck;

    const int fl = lane & 15;
    const int kb = (lane >> 4) * 8;

    for (int k0 = 0; k0 < kchunk; k0 += 32) {
        u32 av = 0;
        if (mA < n) av = *reinterpret_cast<const u32*>(pA);
        pA += 32;
        gload16(pB0, &Bs[w * 32 + 0][0]);
        gload16(pB1, &Bs[w * 32 + 16][0]);
        pB0 += 32; pB1 += 32;
        *reinterpret_cast<u32*>(&As[arow][ak]) = av;
        __syncthreads();

        bf16x8 a  = *reinterpret_cast<const bf16x8*>(&As[fl][kb]);
        bf16x8 b0 = *reinterpret_cast<const bf16x8*>(&Bs[w * 32 + 0  + fl][kb]);
        bf16x8 b1 = *reinterpret_cast<const bf16x8*>(&Bs[w * 32 + 16 + fl][kb]);
        acc0 = __builtin_amdgcn_mfma_f32_16x16x32_bf16(a, b0, acc0, 0, 0, 0);
        acc1 = __builtin_amdgcn_mfma_f32_16x16x32_bf16(a, b1, acc1, 0, 0, 0);
        __syncthreads();
    }

    const int rg = (lane >> 4) * 4;
    float* gout = partials + (size_t)ks * n * GCOLS;
    #pragma unroll
    for (int r = 0; r < 4; ++r) {
        const int m = m0 + rg + r;
        if (m < n) {
            gout[(size_t)m * GCOLS + c0 + w * 32 + 0  + fl] = acc0[r];
            gout[(size_t)m * GCOLS + c0 + w * 32 + 16 + fl] = acc1[r];
        }
    }
}

// ---------------------------------------------------------------- LSTM cell
// Sums KS partial slabs + bias, applies cell. Writes h (bf16) directly into
// the NEXT level's Xcat slab h-region, c (f32) flat.
__global__ void level_act(const float* __restrict__ gsrc, int ks_n, size_t ks_stride,
                          const float* __restrict__ bg,
                          const float* __restrict__ cprev,   // prev level c, flat
                          u16* __restrict__ hXcat,           // next slab base (or null at k=0)
                          float* __restrict__ cb_next,       // n x 1024 f32
                          float* __restrict__ out,           // null unless n==1
                          int n, int has_h)
{
    int idx = blockIdx.x * blockDim.x + threadIdx.x;   // over n*256
    if (idx >= n * 256) return;
    int m = idx >> 8, j4 = (idx & 255) * 4;

    float4 iv = *reinterpret_cast<const float4*>(bg + j4);
    float4 fv = *reinterpret_cast<const float4*>(bg + 1024 + j4);
    float4 gv = *reinterpret_cast<const float4*>(bg + 2048 + j4);
    float4 ov = *reinterpret_cast<const float4*>(bg + 3072 + j4);
    for (int s = 0; s < ks_n; ++s) {
        const float* p = gsrc + (size_t)s * ks_stride + (size_t)m * GCOLS;
        float4 a = *reinterpret_cast<const float4*>(p + j4);
        float4 b = *reinterpret_cast<const float4*>(p + 1024 + j4);
        float4 c = *reinterpret_cast<const float4*>(p + 2048 + j4);
        float4 d = *reinterpret_cast<const float4*>(p + 3072 + j4);
        iv.x += a.x; iv.y += a.y; iv.z += a.z; iv.w += a.w;
        fv.x += b.x; fv.y += b.y; fv.z += b.z; fv.w += b.w;
        gv.x += c.x; gv.y += c.y; gv.z += c.z; gv.w += c.w;
        ov.x += d.x; ov.y += d.y; ov.z += d.z; ov.w += d.w;
    }
    float4 cc = make_float4(0.f, 0.f, 0.f, 0.f);
    if (has_h) cc = *reinterpret_cast<const float4*>(cprev + (size_t)m * 2048 + j4);

    float cn[4], hn[4];
    float ivv[4] = {iv.x, iv.y, iv.z, iv.w};
    float fvv[4] = {fv.x, fv.y, fv.z, fv.w};
    float gvv[4] = {gv.x, gv.y, gv.z, gv.w};
    float ovv[4] = {ov.x, ov.y, ov.z, ov.w};
    float ccv[4] = {cc.x, cc.y, cc.z, cc.w};
    #pragma unroll
    for (int t = 0; t < 4; ++t) {
        float si = 1.0f / (1.0f + expf(-ivv[t]));
        float sf = 1.0f / (1.0f + expf(-fvv[t]));
        float so = 1.0f / (1.0f + expf(-ovv[t]));
        cn[t] = sf * ccv[t] + si * tanhf(gvv[t]);
        hn[t] = so * tanhf(cn[t]);
    }
    if (hXcat) {
        uint2 hp = make_uint2((u32)f2bf(hn[0]) | ((u32)f2bf(hn[1]) << 16),
                              (u32)f2bf(hn[2]) | ((u32)f2bf(hn[3]) << 16));
        // h of node m -> next-level row m>>1, col 1024 + (m&1)*1024 + j4
        *reinterpret_cast<uint2*>(hXcat + (size_t)(m >> 1) * 3072 +
                                  1024 + (m & 1) * 1024 + j4) = hp;
    }
    *reinterpret_cast<float4*>(cb_next + (size_t)m * HDIM + j4) =
        make_float4(cn[0], cn[1], cn[2], cn[3]);
    if (out) {
        *reinterpret_cast<float4*>(out + j4) = make_float4(hn[0], hn[1], hn[2], hn[3]);
        *reinterpret_cast<float4*>(out + 1024 + j4) = make_float4(cn[0], cn[1], cn[2], cn[3]);
    }
}

// ---------------------------------------------------------------- launcher
extern "C" void kernel_launch(void* const* d_in, const int* in_sizes, int n_in,
                              void* d_out, int out_size, void* d_ws, size_t ws_size,
                              hipStream_t stream) {
    const float* emb  = (const float*)d_in[0];
    const float* W_ih = (const float*)d_in[1];
    const float* W_hh = (const float*)d_in[2];
    const float* b_ih = (const float*)d_in[3];
    const float* b_hh = (const float*)d_in[4];
    float* out = (float*)d_out;

    char* p = (char*)d_ws;
    float* bg    = (float*)p;   p += 16384;
    u16* Wcat    = (u16*)p;     p += (size_t)4096 * 3072 * 2;   // 25.2 MB
    u16* Xcat    = (u16*)p;     p += (size_t)4096 * 3072 * 2;   // 25.2 MB (4095 used)
    float* gates = (float*)p;   p += (size_t)2048 * 4096 * 4;   // 33.6 MB partial slabs
    float* cb0   = (float*)p;   p += (size_t)2048 * 1024 * 4;
    float* cb1   = (float*)p;   p += (size_t)2048 * 1024 * 4;

    bias_kernel<<<16, 256, 0, stream>>>(b_ih, b_hh, bg);
    {
        dim3 g(4096, 3);
        pack_w<<<g, 256, 0, stream>>>(W_ih, W_hh, Wcat);
    }
    conv_emb_cat<<<4095, 256, 0, stream>>>(emb, Xcat);

    const float* cprev = nullptr;
    int buf = 0;
    for (int k = TREE_DEPTH - 1; k >= 0; --k) {
        const int n = 1 << k;
        const int has_h = (k != TREE_DEPTH - 1);
        const int Ktot = has_h ? 3072 : 1024;
        const u16* A = Xcat + (size_t)(4096 - (2 << k)) * 3072;
        u16* hXn = (k > 0) ? (Xcat + (size_t)(4096 - (1 << k)) * 3072) : nullptr;
        float* cn = buf ? cb1 : cb0;
        float* outp = (k == 0) ? out : nullptr;

        int KS;
        if (n >= 128) {
            // K-split for >=256 blocks; gy*KS divisible by 8 in all cases.
            KS = (k == 11) ? 1 : (k == 10) ? 2 : (k == 9) ? 4 : (k == 8) ? 8 : 16;
            dim3 grid(n / 128, GCOLS / 128, KS);
            gemm_big<<<grid, 256, 0, stream>>>(A, Wcat, gates, n, Ktot / KS);
        } else {
            KS = (n >= 32) ? 8 : 16;
            dim3 grid((n + 15) / 16, GCOLS / 128, KS);
            gemm_small<<<grid, 256, 0, stream>>>(A, Wcat, gates, n, Ktot / KS);
        }
        const int tot = n * 256;
        level_act<<<(tot + 255) / 256, 256, 0, stream>>>(
            gates, KS, (size_t)n * GCOLS, bg, cprev, hXn, cn, outp, n, has_h);

        cprev = cn; buf ^= 1;
    }
}